// Round 8
// baseline (927.464 us; speedup 1.0000x reference)
//
#include <hip/hip_runtime.h>
#include <math.h>

// GCN generator: B=8, N=F=128. One block/batch, 1024 threads (16 waves).
// Round 8: identical structure to round 7 (2 barriers/step), ONE change:
// amdgpu_waves_per_eu(4,4) pins the allocator to the real occupancy
// (16 waves/CU = 4/EU; LDS limits to 1 block/CU) so it stops targeting
// 8 waves/EU with a 64-VGPR budget (round-7 counters: VGPR=64 exactly,
// ~2MB unexplained WRITE_SIZE = remat/spill suspicion).
//   P2: z=(D M D)u + d^2 u fused update + relu + ssq + z->X
//   P4: mm_a u=(dv.z).W -> U (all waves) || wave0: pd/probs/degrees/patches.

#define NN 128
#define SP 136

typedef _Float16 f16;
typedef _Float16 f16x8 __attribute__((ext_vector_type(8)));
typedef _Float16 f16x4 __attribute__((ext_vector_type(4)));
typedef _Float16 f16x2 __attribute__((ext_vector_type(2)));
typedef float f32x4 __attribute__((ext_vector_type(4)));

__device__ __forceinline__ f32x4 mm(f16x8 a, f16x8 b, f32x4 c) {
    return __builtin_amdgcn_mfma_f32_16x16x32_f16(a, b, c, 0, 0, 0);
}

__device__ __forceinline__ float rowdot8(f16x8 g, float acc) {
#if __has_builtin(__builtin_amdgcn_fdot2)
    const f16x2 one2 = {(f16)1.0f, (f16)1.0f};
    #pragma unroll
    for (int p = 0; p < 4; ++p) {
        f16x2 pr = {g[2*p], g[2*p+1]};
        acc = __builtin_amdgcn_fdot2(pr, one2, acc, false);
    }
#else
    #pragma unroll
    for (int e = 0; e < 8; ++e) acc += (float)g[e];
#endif
    return acc;
}

__device__ __forceinline__ float dot8(f16x8 a, f16x8 b, float acc) {
#if __has_builtin(__builtin_amdgcn_fdot2)
    #pragma unroll
    for (int p = 0; p < 4; ++p) {
        f16x2 pa = {a[2*p], a[2*p+1]};
        f16x2 pb = {b[2*p], b[2*p+1]};
        acc = __builtin_amdgcn_fdot2(pa, pb, acc, false);
    }
#else
    #pragma unroll
    for (int e = 0; e < 8; ++e) acc += (float)a[e]*(float)b[e];
#endif
    return acc;
}

__global__ __launch_bounds__(1024)
__attribute__((amdgpu_waves_per_eu(4, 4)))
void gcn_gen_kernel(const float* __restrict__ gx,
                    const float* __restrict__ gW,
                    const float* __restrict__ gb,
                    float* __restrict__ gout)
{
    extern __shared__ char lds_raw[];
    f16* X     = (f16*)lds_raw;              // [128][136] UNNORM z [n][f]
    f16* U     = X + NN*SP;                  // [128][136] u = x_hat.W, [fo][m]
    f16* Gb0   = U + NN*SP;                  // [128][136] M-hat ping
    f16* Gb1   = Gb0 + NN*SP;                // [128][136] M-hat pong
    f16* s_df16  = Gb1 + NN*SP;              // [128] d (f16)
    float* s_d    = (float*)(s_df16 + NN);   // [128] d (f32)
    float* s_diag = s_d + NN;                // [128] diag of carried C
    float* s_rows = s_diag + NN;             // [4][128] rowsum quarters
    float* s_ssq  = s_rows + 4*NN;           // [4][128] ssq partials by wc

    const int b = blockIdx.x;
    const int t = threadIdx.x;
    const int lane = t & 63;
    const int w = t >> 6;
    const int wr = w >> 2, wc = w & 3;       // wave grid 4x4 (32x32 tile)
    const int lrow = lane & 15;
    const int lgrp = lane >> 4;

    const float* xb = gx + (size_t)b*NN*NN;
    float* outb = gout + (size_t)b*NN*NN;

    const float bias0 = gb[wc*32 + lrow];
    const float bias1 = gb[wc*32 + 16 + lrow];

    // ---- W -> registers as B-fragments for mm_a (k=fi, col=fo) ----
    f16x8 Wh[4][2];
    #pragma unroll
    for (int ks = 0; ks < 4; ++ks)
    #pragma unroll
    for (int ct = 0; ct < 2; ++ct) {
        const int col = wc*32 + ct*16 + lrow;
        #pragma unroll
        for (int r = 0; r < 8; ++r)
            Wh[ks][ct][r] = (f16)gW[(ks*32 + lgrp*8 + r)*NN + col];
    }

    // ---- init: X = f16(x), G0 = I(raw), out = eye, vectors ----
    #pragma unroll
    for (int q = 0; q < 16; ++q) {
        int idx = q*1024 + t;
        int r = idx >> 7, c = idx & 127;
        float e = (r == c) ? 1.f : 0.f;
        X[r*SP + c] = (f16)xb[idx];
        Gb0[r*SP + c] = (f16)e;
        outb[idx] = e;
    }
    if (t < NN) {
        s_d[t] = 0.70710678f;
        s_df16[t] = (f16)0.70710678f;
        s_diag[t] = 1.f;
    }
    __syncthreads();

    // mm_a: u = (sv . X) . W  -> U[fo][m]  (sv = per-row scale, f16)
    auto run_mma = [&](f16 sv0, f16 sv1) {
        f32x4 a2[2][2];
        #pragma unroll
        for (int rt = 0; rt < 2; ++rt)
        #pragma unroll
        for (int ct = 0; ct < 2; ++ct)
            a2[rt][ct] = (f32x4){0.f,0.f,0.f,0.f};
        #pragma unroll
        for (int ks = 0; ks < 4; ++ks) {
            const int ko = ks*32 + lgrp*8;
            f16x8 A0 = *(const f16x8*)(X + (wr*32 + lrow)*SP + ko) * sv0;
            f16x8 A1 = *(const f16x8*)(X + (wr*32 + 16 + lrow)*SP + ko) * sv1;
            a2[0][0] = mm(A0, Wh[ks][0], a2[0][0]);
            a2[0][1] = mm(A0, Wh[ks][1], a2[0][1]);
            a2[1][0] = mm(A1, Wh[ks][0], a2[1][0]);
            a2[1][1] = mm(A1, Wh[ks][1], a2[1][1]);
        }
        #pragma unroll
        for (int rt = 0; rt < 2; ++rt)
        #pragma unroll
        for (int ct = 0; ct < 2; ++ct) {
            f16x4 uv;
            #pragma unroll
            for (int q = 0; q < 4; ++q) uv[q] = (f16)a2[rt][ct][q];
            *(f16x4*)(U + (wc*32 + ct*16 + lrow)*SP + wr*32 + rt*16 + lgrp*4) = uv;
        }
    };
    run_mma((f16)1.0f, (f16)1.0f);
    __syncthreads();

    for (int i = 0; i < NN; ++i) {
        const int pn = i + 1;
        f16* Gc = (i & 1) ? Gb1 : Gb0;       // M-hat (patched C_{i-1})
        f16* Gn = (i & 1) ? Gb0 : Gb1;       // receives scaled carry C_i

        // ========== P2: z = (D M D) u + d^2 u, fused update ==========
        f16x8 dcv[4];
        #pragma unroll
        for (int ks = 0; ks < 4; ++ks)
            dcv[ks] = *(const f16x8*)(s_df16 + ks*32 + lgrp*8);
        const f16 drh0 = s_df16[wr*32 + lrow];
        const f16 drh1 = s_df16[wr*32 + 16 + lrow];

        f32x4 acc[2][2];
        #pragma unroll
        for (int rt = 0; rt < 2; ++rt)
        #pragma unroll
        for (int ct = 0; ct < 2; ++ct)
            acc[rt][ct] = (f32x4){0.f,0.f,0.f,0.f};
        float rs0 = 0.f, rs1 = 0.f;
        #pragma unroll
        for (int ks = 0; ks < 4; ++ks) {
            const int ko = ks*32 + lgrp*8;
            f16x8 B0 = *(const f16x8*)(U + (wc*32 + lrow)*SP + ko);
            f16x8 B1 = *(const f16x8*)(U + (wc*32 + 16 + lrow)*SP + ko);
            f16x8 A0 = *(const f16x8*)(Gc + (wr*32 + lrow)*SP + ko);
            f16x8 A1 = *(const f16x8*)(Gc + (wr*32 + 16 + lrow)*SP + ko);
            f16x8 G0s = A0 * dcv[ks] * drh0;
            f16x8 G1s = A1 * dcv[ks] * drh1;
            acc[0][0] = mm(G0s, B0, acc[0][0]);
            acc[0][1] = mm(G0s, B1, acc[0][1]);
            acc[1][0] = mm(G1s, B0, acc[1][0]);
            acc[1][1] = mm(G1s, B1, acc[1][1]);
            if (ks == wc) {                   // own quarter: carry + rowsum
                *(f16x8*)(Gn + (wr*32 + lrow)*SP + ko) = G0s;
                *(f16x8*)(Gn + (wr*32 + 16 + lrow)*SP + ko) = G1s;
                rs0 = rowdot8(G0s, rs0);
                rs1 = rowdot8(G1s, rs1);
            }
        }
        rs0 += __shfl_xor(rs0, 16); rs0 += __shfl_xor(rs0, 32);
        rs1 += __shfl_xor(rs1, 16); rs1 += __shfl_xor(rs1, 32);
        if (lgrp == 0) {
            s_rows[wc*NN + wr*32 + lrow]      = rs0;
            s_rows[wc*NN + wr*32 + 16 + lrow] = rs1;
        }

        // z = acc + d_r^2 * u_rc + bias, relu; store UNNORM z -> X
        const float4 dr4a = *(const float4*)(s_d + wr*32 + lgrp*4);
        const float4 dr4b = *(const float4*)(s_d + wr*32 + 16 + lgrp*4);
        float z[2][2][4];
        #pragma unroll
        for (int rt = 0; rt < 2; ++rt)
        #pragma unroll
        for (int ct = 0; ct < 2; ++ct) {
            f16x4 u4 = *(const f16x4*)(U + (wc*32 + ct*16 + lrow)*SP
                                         + wr*32 + rt*16 + lgrp*4);
            const int col = wc*32 + ct*16 + lrow;
            #pragma unroll
            for (int q = 0; q < 4; ++q) {
                float dq = rt ? ((const float*)&dr4b)[q] : ((const float*)&dr4a)[q];
                float zv = fmaxf(acc[rt][ct][q] + dq*dq*(float)u4[q]
                                 + (ct ? bias1 : bias0), 0.f);
                z[rt][ct][q] = zv;
                X[(wr*32 + rt*16 + lgrp*4 + q)*SP + col] = (f16)zv;
            }
        }
        {
            float ss[8];
            #pragma unroll
            for (int k = 0; k < 8; ++k) {
                float a = z[k>>2][0][k&3], c2 = z[k>>2][1][k&3];
                ss[k] = a*a + c2*c2;
            }
            #pragma unroll
            for (int k = 0; k < 8; ++k) {
                ss[k] += __shfl_xor(ss[k], 1);
                ss[k] += __shfl_xor(ss[k], 2);
                ss[k] += __shfl_xor(ss[k], 4);
                ss[k] += __shfl_xor(ss[k], 8);
            }
            if (lrow == 0) {
                #pragma unroll
                for (int k = 0; k < 8; ++k) {
                    int row = wr*32 + (k>>2)*16 + lgrp*4 + (k&3);
                    s_ssq[wc*NN + row] = ss[k];
                }
            }
        }
        __syncthreads();

        // ========== P4: mm_a (dv-scaled) || wave0 serial ==========
        if (pn < NN) {
            f16 dvh[2];
            #pragma unroll
            for (int rt = 0; rt < 2; ++rt) {
                const int row = wr*32 + rt*16 + lrow;
                float sq = s_ssq[row] + s_ssq[NN+row] + s_ssq[2*NN+row] + s_ssq[3*NN+row];
                float dv = (i == 0) ? 1.f : 1.f/(sqrtf(sq) + 1e-8f);
                dvh[rt] = (f16)fminf(dv, 60000.f);
            }
            run_mma(dvh[0], dvh[1]);

            if (w == 0) {
                float sqp = s_ssq[pn] + s_ssq[NN+pn] + s_ssq[2*NN+pn] + s_ssq[3*NN+pn];
                float dp = (i == 0) ? 1.f : 1.f/(sqrtf(sqp) + 1e-8f);
                float pv[2], rsC[2];
                float sp = 0.f;
                #pragma unroll
                for (int h = 0; h < 2; ++h) {
                    const int tt = lane + h*64;
                    float p = 0.f;
                    if (tt < pn) {
                        const f16* Xr = X + tt*SP;
                        const f16* Xp = X + pn*SP;
                        float a0 = 0.f, a1 = 0.f, a2 = 0.f, a3 = 0.f;
                        #pragma unroll
                        for (int c = 0; c < 4; ++c) {
                            a0 = dot8(*(const f16x8*)(Xr + c*32),
                                      *(const f16x8*)(Xp + c*32), a0);
                            a1 = dot8(*(const f16x8*)(Xr + c*32 + 8),
                                      *(const f16x8*)(Xp + c*32 + 8), a1);
                            a2 = dot8(*(const f16x8*)(Xr + c*32 + 16),
                                      *(const f16x8*)(Xp + c*32 + 16), a2);
                            a3 = dot8(*(const f16x8*)(Xr + c*32 + 24),
                                      *(const f16x8*)(Xp + c*32 + 24), a3);
                        }
                        float zd = (a0 + a1) + (a2 + a3);
                        float sqj = s_ssq[tt] + s_ssq[NN+tt] + s_ssq[2*NN+tt] + s_ssq[3*NN+tt];
                        float dj = (i == 0) ? 1.f : 1.f/(sqrtf(sqj) + 1e-8f);
                        p = 1.f/(1.f + expf(-0.5f*zd*dj*dp));
                        sp += p;
                        outb[pn*NN + tt] = p;
                        outb[tt*NN + pn] = p;
                    }
                    pv[h] = p;
                    float dold = s_d[tt];
                    rsC[h] = s_rows[tt] + s_rows[NN+tt] + s_rows[2*NN+tt] + s_rows[3*NN+tt]
                           + dold*dold;                   // rowsum(C_i)_t
                }
                #pragma unroll
                for (int m2 = 1; m2 < 64; m2 <<= 1) sp += __shfl_xor(sp, m2);
                #pragma unroll
                for (int h = 0; h < 2; ++h) {
                    const int tt = lane + h*64;
                    float dgC = s_diag[tt];                // diag(C_i)_t
                    float rsM = (tt < pn) ? (rsC[h] + pv[h])
                              : ((tt == pn) ? (sp + dgC) : rsC[h]);
                    float dnew = 1.f/sqrtf(rsM + 1.f + 1e-8f);
                    s_d[tt] = dnew;
                    s_df16[tt] = (f16)dnew;
                    s_diag[tt] = dnew*dnew*(dgC + 1.f);    // diag(C_{i+1})
                    Gn[tt*SP + tt] = (f16)dgC;             // fix stored diag
                    if (tt < pn) {                         // patch row/col pn
                        f16 pf = (f16)pv[h];
                        Gn[pn*SP + tt] = pf;
                        Gn[tt*SP + pn] = pf;
                    }
                }
            }
        }
        __syncthreads();
    }
}

extern "C" void kernel_launch(void* const* d_in, const int* in_sizes, int n_in,
                              void* d_out, int out_size, void* d_ws, size_t ws_size,
                              hipStream_t stream) {
    const float* x  = (const float*)d_in[0];
    const float* W  = (const float*)d_in[1];
    const float* bb = (const float*)d_in[2];
    float* out = (float*)d_out;

    const size_t shmem = (size_t)(4*NN*SP + NN)*sizeof(f16)
                       + (size_t)(2*NN + 4*NN + 4*NN)*sizeof(float);
    hipFuncSetAttribute((const void*)gcn_gen_kernel,
                        hipFuncAttributeMaxDynamicSharedMemorySize, (int)shmem);
    gcn_gen_kernel<<<8, 1024, shmem, stream>>>(x, W, bb, out);
}

// Round 9
// 795.151 us; speedup vs baseline: 1.1664x; 1.1664x over previous
//
#include <hip/hip_runtime.h>
#include <math.h>

// GCN generator: B=8, N=F=128. One block/batch, 1024 threads (16 waves).
// Round 9: 3 barriers/step, serial tail distributed.
//   P2: z = dr*(M.(d*u)) + dr^2 u fused + relu + ssq + z->X (+own-quarter
//       carry writeback & rowsums). u carried in f32 regs from last mm_a.
//   P4: mm_a u=(dv.z).W -> U (16 waves) + t<128: full-row dot vs pivot,
//       sigmoid, out writes, Gn row/col patches.
//   P4c: t<128: sp butterfly, degrees, diag track, Gn diag fix.

#define NN 128
#define SP 136

typedef _Float16 f16;
typedef _Float16 f16x8 __attribute__((ext_vector_type(8)));
typedef _Float16 f16x4 __attribute__((ext_vector_type(4)));
typedef _Float16 f16x2 __attribute__((ext_vector_type(2)));
typedef float f32x4 __attribute__((ext_vector_type(4)));

__device__ __forceinline__ f32x4 mm(f16x8 a, f16x8 b, f32x4 c) {
    return __builtin_amdgcn_mfma_f32_16x16x32_f16(a, b, c, 0, 0, 0);
}

__device__ __forceinline__ float rowdot8(f16x8 g, float acc) {
#if __has_builtin(__builtin_amdgcn_fdot2)
    const f16x2 one2 = {(f16)1.0f, (f16)1.0f};
    #pragma unroll
    for (int p = 0; p < 4; ++p) {
        f16x2 pr = {g[2*p], g[2*p+1]};
        acc = __builtin_amdgcn_fdot2(pr, one2, acc, false);
    }
#else
    #pragma unroll
    for (int e = 0; e < 8; ++e) acc += (float)g[e];
#endif
    return acc;
}

__device__ __forceinline__ float dot8(f16x8 a, f16x8 b, float acc) {
#if __has_builtin(__builtin_amdgcn_fdot2)
    #pragma unroll
    for (int p = 0; p < 4; ++p) {
        f16x2 pa = {a[2*p], a[2*p+1]};
        f16x2 pb = {b[2*p], b[2*p+1]};
        acc = __builtin_amdgcn_fdot2(pa, pb, acc, false);
    }
#else
    #pragma unroll
    for (int e = 0; e < 8; ++e) acc += (float)a[e]*(float)b[e];
#endif
    return acc;
}

__global__ __launch_bounds__(1024)
__attribute__((amdgpu_waves_per_eu(4, 4)))
void gcn_gen_kernel(const float* __restrict__ gx,
                    const float* __restrict__ gW,
                    const float* __restrict__ gb,
                    float* __restrict__ gout)
{
    extern __shared__ char lds_raw[];
    f16* X     = (f16*)lds_raw;              // [128][136] UNNORM z [n][f]
    f16* U     = X + NN*SP;                  // [128][136] u = x_hat.W, [fo][m]
    f16* Gb0   = U + NN*SP;                  // [128][136] M-hat ping
    f16* Gb1   = Gb0 + NN*SP;                // [128][136] M-hat pong
    f16* s_df16  = Gb1 + NN*SP;              // [128] d (f16)
    float* s_d    = (float*)(s_df16 + NN);   // [128] d (f32)
    float* s_diag = s_d + NN;                // [128] diag of carried C
    float* s_prob = s_diag + NN;             // [128] probs this step
    float* s_rows = s_prob + NN;             // [4][128] rowsum quarters
    float* s_ssq  = s_rows + 4*NN;           // [4][128] ssq partials by wc

    const int b = blockIdx.x;
    const int t = threadIdx.x;
    const int lane = t & 63;
    const int w = t >> 6;
    const int wr = w >> 2, wc = w & 3;       // wave grid 4x4 (32x32 tile)
    const int lrow = lane & 15;
    const int lgrp = lane >> 4;

    const float* xb = gx + (size_t)b*NN*NN;
    float* outb = gout + (size_t)b*NN*NN;

    const float bias0 = gb[wc*32 + lrow];
    const float bias1 = gb[wc*32 + 16 + lrow];

    // ---- W -> registers as B-fragments for mm_a (k=fi, col=fo) ----
    f16x8 Wh[4][2];
    #pragma unroll
    for (int ks = 0; ks < 4; ++ks)
    #pragma unroll
    for (int ct = 0; ct < 2; ++ct) {
        const int col = wc*32 + ct*16 + lrow;
        #pragma unroll
        for (int r = 0; r < 8; ++r)
            Wh[ks][ct][r] = (f16)gW[(ks*32 + lgrp*8 + r)*NN + col];
    }

    // ---- init: X = f16(x), G0 = I(raw), out = eye, vectors ----
    #pragma unroll
    for (int q = 0; q < 16; ++q) {
        int idx = q*1024 + t;
        int r = idx >> 7, c = idx & 127;
        float e = (r == c) ? 1.f : 0.f;
        X[r*SP + c] = (f16)xb[idx];
        Gb0[r*SP + c] = (f16)e;
        outb[idx] = e;
    }
    if (t < NN) {
        s_d[t] = 0.70710678f;
        s_df16[t] = (f16)0.70710678f;
        s_diag[t] = 1.f;
    }
    __syncthreads();

    // mm_a: u = (sv . X) . W -> U[fo][m] (f16) AND au regs (f32, own tile)
    f32x4 au[2][2];
    auto run_mma = [&](f16 sv0, f16 sv1) {
        f32x4 a2[2][2];
        #pragma unroll
        for (int rt = 0; rt < 2; ++rt)
        #pragma unroll
        for (int ct = 0; ct < 2; ++ct)
            a2[rt][ct] = (f32x4){0.f,0.f,0.f,0.f};
        #pragma unroll
        for (int ks = 0; ks < 4; ++ks) {
            const int ko = ks*32 + lgrp*8;
            f16x8 A0 = *(const f16x8*)(X + (wr*32 + lrow)*SP + ko) * sv0;
            f16x8 A1 = *(const f16x8*)(X + (wr*32 + 16 + lrow)*SP + ko) * sv1;
            a2[0][0] = mm(A0, Wh[ks][0], a2[0][0]);
            a2[0][1] = mm(A0, Wh[ks][1], a2[0][1]);
            a2[1][0] = mm(A1, Wh[ks][0], a2[1][0]);
            a2[1][1] = mm(A1, Wh[ks][1], a2[1][1]);
        }
        #pragma unroll
        for (int rt = 0; rt < 2; ++rt)
        #pragma unroll
        for (int ct = 0; ct < 2; ++ct) {
            f16x4 uv;
            #pragma unroll
            for (int q = 0; q < 4; ++q) uv[q] = (f16)a2[rt][ct][q];
            *(f16x4*)(U + (wc*32 + ct*16 + lrow)*SP + wr*32 + rt*16 + lgrp*4) = uv;
            au[rt][ct] = a2[rt][ct];
        }
    };
    run_mma((f16)1.0f, (f16)1.0f);
    __syncthreads();

    for (int i = 0; i < NN; ++i) {
        const int pn = i + 1;
        f16* Gc = (i & 1) ? Gb1 : Gb0;       // M-hat (patched C_{i-1})
        f16* Gn = (i & 1) ? Gb0 : Gb1;       // receives scaled carry C_i

        // ========== P2: z = dr*(M.(d*u)) + dr^2 u, fused update ==========
        f16x8 dcv[4];
        #pragma unroll
        for (int ks = 0; ks < 4; ++ks)
            dcv[ks] = *(const f16x8*)(s_df16 + ks*32 + lgrp*8);
        const f16 drh0 = s_df16[wr*32 + lrow];
        const f16 drh1 = s_df16[wr*32 + 16 + lrow];

        f32x4 acc[2][2];
        #pragma unroll
        for (int rt = 0; rt < 2; ++rt)
        #pragma unroll
        for (int ct = 0; ct < 2; ++ct)
            acc[rt][ct] = (f32x4){0.f,0.f,0.f,0.f};
        float rs0 = 0.f, rs1 = 0.f;
        #pragma unroll
        for (int ks = 0; ks < 4; ++ks) {
            const int ko = ks*32 + lgrp*8;
            f16x8 B0 = *(const f16x8*)(U + (wc*32 + lrow)*SP + ko) * dcv[ks];
            f16x8 B1 = *(const f16x8*)(U + (wc*32 + 16 + lrow)*SP + ko) * dcv[ks];
            f16x8 A0 = *(const f16x8*)(Gc + (wr*32 + lrow)*SP + ko);
            f16x8 A1 = *(const f16x8*)(Gc + (wr*32 + 16 + lrow)*SP + ko);
            acc[0][0] = mm(A0, B0, acc[0][0]);
            acc[0][1] = mm(A0, B1, acc[0][1]);
            acc[1][0] = mm(A1, B0, acc[1][0]);
            acc[1][1] = mm(A1, B1, acc[1][1]);
            if (ks == wc) {                   // own quarter: carry + rowsum
                f16x8 G0s = A0 * dcv[ks] * drh0;
                f16x8 G1s = A1 * dcv[ks] * drh1;
                *(f16x8*)(Gn + (wr*32 + lrow)*SP + ko) = G0s;
                *(f16x8*)(Gn + (wr*32 + 16 + lrow)*SP + ko) = G1s;
                rs0 = rowdot8(G0s, rs0);
                rs1 = rowdot8(G1s, rs1);
            }
        }
        rs0 += __shfl_xor(rs0, 16); rs0 += __shfl_xor(rs0, 32);
        rs1 += __shfl_xor(rs1, 16); rs1 += __shfl_xor(rs1, 32);
        if (lgrp == 0) {
            s_rows[wc*NN + wr*32 + lrow]      = rs0;
            s_rows[wc*NN + wr*32 + 16 + lrow] = rs1;
        }

        // z = dr*(acc + dr*u) + bias, relu; store UNNORM z -> X
        const float4 dr4a = *(const float4*)(s_d + wr*32 + lgrp*4);
        const float4 dr4b = *(const float4*)(s_d + wr*32 + 16 + lgrp*4);
        float z[2][2][4];
        #pragma unroll
        for (int rt = 0; rt < 2; ++rt)
        #pragma unroll
        for (int ct = 0; ct < 2; ++ct) {
            const int col = wc*32 + ct*16 + lrow;
            #pragma unroll
            for (int q = 0; q < 4; ++q) {
                float dq = rt ? ((const float*)&dr4b)[q] : ((const float*)&dr4a)[q];
                float inner = fmaf(dq, au[rt][ct][q], acc[rt][ct][q]);
                float zv = fmaxf(fmaf(dq, inner, (ct ? bias1 : bias0)), 0.f);
                z[rt][ct][q] = zv;
                X[(wr*32 + rt*16 + lgrp*4 + q)*SP + col] = (f16)zv;
            }
        }
        {
            float ss[8];
            #pragma unroll
            for (int k = 0; k < 8; ++k) {
                float a = z[k>>2][0][k&3], c2 = z[k>>2][1][k&3];
                ss[k] = a*a + c2*c2;
            }
            #pragma unroll
            for (int k = 0; k < 8; ++k) {
                ss[k] += __shfl_xor(ss[k], 1);
                ss[k] += __shfl_xor(ss[k], 2);
                ss[k] += __shfl_xor(ss[k], 4);
                ss[k] += __shfl_xor(ss[k], 8);
            }
            if (lrow == 0) {
                #pragma unroll
                for (int k = 0; k < 8; ++k) {
                    int row = wr*32 + (k>>2)*16 + lgrp*4 + (k&3);
                    s_ssq[wc*NN + row] = ss[k];
                }
            }
        }
        __syncthreads();

        // ========== P4: mm_a (dv-scaled, 16 waves) + t<128 prob rows ======
        float p_keep = 0.f;
        if (pn < NN) {
            f16 dvh[2];
            #pragma unroll
            for (int rt = 0; rt < 2; ++rt) {
                const int row = wr*32 + rt*16 + lrow;
                float sq = s_ssq[row] + s_ssq[NN+row] + s_ssq[2*NN+row] + s_ssq[3*NN+row];
                float dv = (i == 0) ? 1.f : 1.f/(sqrtf(sq) + 1e-8f);
                dvh[rt] = (f16)fminf(dv, 60000.f);
            }
            run_mma(dvh[0], dvh[1]);

            if (t < NN) {
                const int tt = t;
                float sqp = s_ssq[pn] + s_ssq[NN+pn] + s_ssq[2*NN+pn] + s_ssq[3*NN+pn];
                float dp = (i == 0) ? 1.f : 1.f/(sqrtf(sqp) + 1e-8f);
                if (tt < pn) {
                    const f16x8* Xr = (const f16x8*)(X + tt*SP);
                    const f16x8* Xp = (const f16x8*)(X + pn*SP);
                    float a0 = 0.f, a1 = 0.f, a2v = 0.f, a3 = 0.f;
                    #pragma unroll
                    for (int c = 0; c < 4; ++c) {
                        a0  = dot8(Xr[c*4 + 0], Xp[c*4 + 0], a0);
                        a1  = dot8(Xr[c*4 + 1], Xp[c*4 + 1], a1);
                        a2v = dot8(Xr[c*4 + 2], Xp[c*4 + 2], a2v);
                        a3  = dot8(Xr[c*4 + 3], Xp[c*4 + 3], a3);
                    }
                    float zd = (a0 + a1) + (a2v + a3);
                    float sqj = s_ssq[tt] + s_ssq[NN+tt] + s_ssq[2*NN+tt] + s_ssq[3*NN+tt];
                    float dj = (i == 0) ? 1.f : 1.f/(sqrtf(sqj) + 1e-8f);
                    p_keep = 1.f/(1.f + expf(-0.5f*zd*dj*dp));
                    f16 pf = (f16)p_keep;
                    outb[pn*NN + tt] = p_keep;
                    outb[tt*NN + pn] = p_keep;
                    Gn[pn*SP + tt] = pf;          // patch row pn
                    Gn[tt*SP + pn] = pf;          // patch col pn
                }
                s_prob[tt] = p_keep;
            }
        }
        __syncthreads();

        // ========== P4c: degrees/diag (t<128), tiny ==========
        if (pn < NN && t < NN) {
            const int tt = t;
            float pa = s_prob[lane];
            float pb = s_prob[lane + 64];
            float sp = ((lane < pn) ? pa : 0.f) + ((lane + 64 < pn) ? pb : 0.f);
            #pragma unroll
            for (int m2 = 1; m2 < 64; m2 <<= 1) sp += __shfl_xor(sp, m2);
            float dold = s_d[tt];
            float rsC = s_rows[tt] + s_rows[NN+tt] + s_rows[2*NN+tt] + s_rows[3*NN+tt]
                      + dold*dold;                    // rowsum(C_i)_t
            float dgC = s_diag[tt];                   // diag(C_i)_t
            float rsM = (tt < pn) ? (rsC + p_keep)
                      : ((tt == pn) ? (sp + dgC) : rsC);
            float dnew = 1.f/sqrtf(rsM + 1.f + 1e-8f);
            s_d[tt] = dnew;
            s_df16[tt] = (f16)dnew;
            s_diag[tt] = dnew*dnew*(dgC + 1.f);       // diag(C_{i+1})
            Gn[tt*SP + tt] = (f16)dgC;                // fix stored diag
        }
        __syncthreads();
    }
}

extern "C" void kernel_launch(void* const* d_in, const int* in_sizes, int n_in,
                              void* d_out, int out_size, void* d_ws, size_t ws_size,
                              hipStream_t stream) {
    const float* x  = (const float*)d_in[0];
    const float* W  = (const float*)d_in[1];
    const float* bb = (const float*)d_in[2];
    float* out = (float*)d_out;

    const size_t shmem = (size_t)(4*NN*SP + NN)*sizeof(f16)
                       + (size_t)(3*NN + 4*NN + 4*NN)*sizeof(float);
    hipFuncSetAttribute((const void*)gcn_gen_kernel,
                        hipFuncAttributeMaxDynamicSharedMemorySize, (int)shmem);
    gcn_gen_kernel<<<8, 1024, shmem, stream>>>(x, W, bb, out);
}